// Round 3
// baseline (704.431 us; speedup 1.0000x reference)
//
#include <hip/hip_runtime.h>

typedef __bf16 bf16;
typedef __bf16 bf16x8 __attribute__((ext_vector_type(8)));
typedef __bf16 bf16x4 __attribute__((ext_vector_type(4)));
typedef __bf16 bf16x2 __attribute__((ext_vector_type(2)));
typedef float f32x4 __attribute__((ext_vector_type(4)));

static __device__ __forceinline__ bf16x8 ld8(const bf16* p) {
    return *reinterpret_cast<const bf16x8*>(p);
}
static __device__ __forceinline__ bf16x4 ld4(const bf16* p) {
    return *reinterpret_cast<const bf16x4*>(p);
}
static __device__ __forceinline__ bf16x8 ld8_b32(const bf16* p) {
    bf16x8 v;
#pragma unroll
    for (int i = 0; i < 4; ++i) {
        bf16x2 t = *reinterpret_cast<const bf16x2*>(p + i * 2);
        v[i * 2] = t[0]; v[i * 2 + 1] = t[1];
    }
    return v;
}
static __device__ __forceinline__ bf16x8 zero8() {
    bf16x8 v;
#pragma unroll
    for (int i = 0; i < 8; ++i) v[i] = (bf16)0.f;
    return v;
}

#define MFMA16(a, b, c) __builtin_amdgcn_mfma_f32_16x16x32_bf16((a), (b), (c), 0, 0, 0)

// Tile movers; LDS row stride 200 elems (conflict-free).
template <int ROWS, int BK, int KPAD, int THREADS>
static __device__ __forceinline__ void load_chunk_g(const bf16* __restrict__ g,
                                                    bf16x8* r, int tid) {
    constexpr int TOT = ROWS * BK / 8;
    constexpr int NP = (TOT + THREADS - 1) / THREADS;
#pragma unroll
    for (int p = 0; p < NP; ++p) {
        int idx = p * THREADS + tid;
        if ((TOT % THREADS) == 0 || idx < TOT) {
            int row = idx / (BK / 8), cg = idx % (BK / 8);
            r[p] = ld8(g + (long)row * KPAD + cg * 8);
        }
    }
}
template <int ROWS, int BK, int THREADS>
static __device__ __forceinline__ void store_chunk_l(bf16* __restrict__ lds,
                                                     const bf16x8* r, int tid) {
    constexpr int TOT = ROWS * BK / 8;
    constexpr int NP = (TOT + THREADS - 1) / THREADS;
#pragma unroll
    for (int p = 0; p < NP; ++p) {
        int idx = p * THREADS + tid;
        if ((TOT % THREADS) == 0 || idx < TOT) {
            int row = idx / (BK / 8), cg = idx % (BK / 8);
            *reinterpret_cast<bf16x8*>(lds + row * 200 + cg * 8) = r[p];
        }
    }
}
template <int ROWS, int BK, int KPAD, int THREADS>
static __device__ __forceinline__ void stage_tile(const bf16* __restrict__ g,
                                                  bf16* __restrict__ lds, int tid) {
    constexpr int TOT = ROWS * BK / 8;
    constexpr int NP = (TOT + THREADS - 1) / THREADS;
#pragma unroll
    for (int p = 0; p < NP; ++p) {
        int idx = p * THREADS + tid;
        if ((TOT % THREADS) == 0 || idx < TOT) {
            int row = idx / (BK / 8), cg = idx % (BK / 8);
            bf16x8 v = ld8(g + (long)row * KPAD + cg * 8);
            *reinterpret_cast<bf16x8*>(lds + row * 200 + cg * 8) = v;
        }
    }
}

#define NBLK 256u

// Device-scope grid barrier: one counter per use (never reset).
static __device__ __forceinline__ void gridbar(unsigned* bar) {
    __threadfence();
    __syncthreads();
    if (threadIdx.x == 0) {
        __hip_atomic_fetch_add(bar, 1u, __ATOMIC_ACQ_REL, __HIP_MEMORY_SCOPE_AGENT);
        while (__hip_atomic_load(bar, __ATOMIC_ACQUIRE, __HIP_MEMORY_SCOPE_AGENT) < NBLK)
            __builtin_amdgcn_s_sleep(2);
    }
    __syncthreads();
    __threadfence();
}

// ---------------------------------------------------------------------------
// One persistent kernel, 256 blocks x 512 threads, 6 phases with grid
// barriers. LDS is a 76.8 KB union re-carved per phase.
// ---------------------------------------------------------------------------
__global__ __launch_bounds__(512, 2) void mega(
    const float* __restrict__ x, const float* __restrict__ y,
    const float* __restrict__ n1g, const float* __restrict__ n1b,
    const float* __restrict__ kv_w, const float* __restrict__ kv_b,
    const float* __restrict__ q_w, const float* __restrict__ q_b,
    const float* __restrict__ rpb, const int* __restrict__ rpi,
    const float* __restrict__ proj_w, const float* __restrict__ proj_b,
    const float* __restrict__ n2g, const float* __restrict__ n2b,
    const float* __restrict__ fc1_w, const float* __restrict__ fc1_b,
    const float* __restrict__ fc2_w, const float* __restrict__ fc2_b,
    bf16* __restrict__ xn, bf16* __restrict__ yn,
    bf16* __restrict__ qbuf, bf16* __restrict__ kvbuf,
    bf16* __restrict__ obuf, float* __restrict__ xo,
    bf16* __restrict__ biast, bf16* __restrict__ wkv, bf16* __restrict__ wq,
    bf16* __restrict__ wproj, bf16* __restrict__ wfc1, bf16* __restrict__ wfc2,
    bf16* __restrict__ hmid, bf16* __restrict__ xn2,
    float* __restrict__ outp, unsigned* __restrict__ bars)
{
    __shared__ __align__(16) char SM[76800];
    const int tid = threadIdx.x;
    const int blk = blockIdx.x;
    const int wave = tid >> 6, lane = tid & 63;
    const int llo = lane & 15, quad = lane >> 4;

    // ================= P0: LayerNorm x|y + weight conv + bias table ========
    {
#pragma unroll 2
        for (int it = 0; it < 16; ++it) {
            int row = blk * 128 + it * 8 + wave;
            const float* sp = (row < 16384) ? (x + (long)row * 180)
                                            : (y + (long)(row - 16384) * 180);
            float v0 = sp[lane];
            float v1 = sp[lane + 64];
            float v2 = (lane < 52) ? sp[lane + 128] : 0.f;
            float s = v0 + v1 + v2;
            float sq = v0 * v0 + v1 * v1 + v2 * v2;
#pragma unroll
            for (int m = 32; m >= 1; m >>= 1) {
                s += __shfl_xor(s, m);
                sq += __shfl_xor(sq, m);
            }
            float mean = s * (1.f / 180.f);
            float var = sq * (1.f / 180.f) - mean * mean;
            float rs = rsqrtf(var + 1e-5f);
            bf16* dp = ((row < 16384) ? xn : (yn - 16384 * 192)) + (long)row * 192;
            dp[lane] = (bf16)((v0 - mean) * rs * n1g[lane] + n1b[lane]);
            dp[lane + 64] = (bf16)((v1 - mean) * rs * n1g[lane + 64] + n1b[lane + 64]);
            float o2 = (lane < 52) ? ((v2 - mean) * rs * n1g[lane + 128] + n1b[lane + 128]) : 0.f;
            dp[lane + 128] = (bf16)o2;
        }
        for (int i = blk * 512 + tid; i < 1392640; i += 131072) {
            if (i < 73728) {                       // wkv
                int n = i / 192, k = i % 192;
                float v = (n < 360 && k < 180) ? kv_w[n * 180 + k] : 0.f;
                wkv[i] = (bf16)v;
            } else if (i < 122880) {               // wq
                int j = i - 73728; int n = j / 192, k = j % 192;
                float v = (n < 180 && k < 180) ? q_w[n * 180 + k] : 0.f;
                wq[j] = (bf16)v;
            } else if (i < 172032) {               // wproj (head-padded K)
                int j = i - 122880; int n = j / 192, k = j % 192;
                int hh = k >> 5, d = k & 31;
                float v = (n < 180 && d < 30) ? proj_w[n * 180 + hh * 30 + d] : 0.f;
                wproj[j] = (bf16)v;
            } else if (i < 319488) {               // wfc1
                int j = i - 172032; int n = j / 192, k = j % 192;
                float v = (n < 720 && k < 180) ? fc1_w[n * 180 + k] : 0.f;
                wfc1[j] = (bf16)v;
            } else if (i < 507904) {               // wfc2
                int j = i - 319488; int n = j / 736, k = j % 736;
                float v = (n < 180 && k < 720) ? fc2_w[n * 720 + k] : 0.f;
                wfc2[j] = (bf16)v;
            } else {                               // bias table, frag-coalesced
                int t = i - 507904;
                int r = t & 3;
                int ln = (t >> 2) & 63;
                int tmp2 = t >> 8;
                int kg = tmp2 % 36;
                int tmp3 = tmp2 / 36;
                int qg = tmp3 & 15;
                int h = tmp3 >> 4;
                int q = qg * 16 + (ln & 15);
                int key = kg * 16 + ((ln >> 4) << 2) + r;
                biast[t] = (bf16)rpb[rpi[q * 576 + key] * 6 + h];
            }
        }
    }
    gridbar(bars + 0);

    // ================= P1: kv + q projection ===============================
    {
        bf16* Sa = (bf16*)SM;             // 128*200
        bf16* Sb = (bf16*)(SM + 51200);   // 64*200
        const int tmi = blk >> 1;
        const int tm = tmi * 128;
        const bool oddb = blk & 1;
        const bf16* A = oddb ? yn : xn;
        stage_tile<128, 192, 192, 512>(A + (long)tm * 192, Sa, tid);
        const int nbz = oddb ? 1 : 2;
        for (int zz = 0; zz < nbz; ++zz) {
            const int bz = oddb ? 2 : zz;
            const bool isq = (bz == 2);
            const bf16* Wbase = isq ? wq : (wkv + (long)bz * 3 * 64 * 192);
            bf16x8 wreg[3];
            load_chunk_g<64, 192, 192, 512>(Wbase, wreg, tid);
            for (int s = 0; s < 3; ++s) {
                if (s || zz) __syncthreads();
                store_chunk_l<64, 192, 512>(Sb, wreg, tid);
                __syncthreads();
                if (s < 2) load_chunk_g<64, 192, 192, 512>(Wbase + (long)(s + 1) * 64 * 192, wreg, tid);

                f32x4 acc[4];
#pragma unroll
                for (int nt = 0; nt < 4; ++nt)
#pragma unroll
                    for (int r = 0; r < 4; ++r) acc[nt][r] = 0.f;
#pragma unroll
                for (int kt = 0; kt < 6; ++kt) {
                    bf16x8 a = ld8(Sa + (wave * 16 + llo) * 200 + kt * 32 + quad * 8);
#pragma unroll
                    for (int nt = 0; nt < 4; ++nt) {
                        bf16x8 b = ld8(Sb + (nt * 16 + llo) * 200 + kt * 32 + quad * 8);
                        acc[nt] = MFMA16(a, b, acc[nt]);
                    }
                }

                const int g = bz * 3 + s;
#pragma unroll
                for (int nt = 0; nt < 4; ++nt) {
                    int n = g * 64 + nt * 16 + llo;
                    if (!isq) {
                        if (n < 360) {
                            int nn = n % 180;
                            int col = (n / 180) * 192 + (nn / 30) * 32 + (nn % 30);
                            float bv = kv_b[n];
#pragma unroll
                            for (int r = 0; r < 4; ++r) {
                                int m = tm + wave * 16 + quad * 4 + r;
                                kvbuf[(long)m * 384 + col] = (bf16)(acc[nt][r] + bv);
                            }
                        }
                    } else {
                        int nq = n - 384;
                        if (nq < 180) {
                            int col = (nq / 30) * 32 + (nq % 30);
                            float bv = q_b[nq];
#pragma unroll
                            for (int r = 0; r < 4; ++r) {
                                int m = tm + wave * 16 + quad * 4 + r;
                                qbuf[(long)m * 192 + col] =
                                    (bf16)((acc[nt][r] + bv) * 0.18257418583505537f);
                            }
                        }
                    }
                }
            }
        }
    }
    gridbar(bars + 1);

    // ================= P2: attention (3 tiles/block, same window) ==========
    {
        bf16 (*Kc)[64][40] = reinterpret_cast<bf16 (*)[64][40]>(SM);
        bf16 (*Vt)[32][74] = reinterpret_cast<bf16 (*)[32][74]>(SM + 10240);
        bf16 (*Ps)[16][72] = reinterpret_cast<bf16 (*)[16][72]>(SM + 19712);

        for (int tt = 0; tt < 3; ++tt) {
            if (tt) __syncthreads();
            const int t = blk * 3 + tt;
            const int win = t / 12, sub = t % 12;
            const int qhalf = sub & 1, head = sub >> 1;
            const int bb = win / 16, wi = (win % 16) / 4, wj = win % 4;
            const int qbase = qhalf * 128 + wave * 16;
            const int qg = qhalf * 8 + wave;

            const int u = tid & 255;
            const int tloc = u >> 2, dq = u & 3;
            const bool isV = tid >= 256;
            int aa = tloc / 24, w0 = tloc % 24;

            const int q0 = qbase + llo;
            const int gr_q = bb * 4096 + (wi * 16 + (q0 >> 4)) * 64 + (wj * 16 + (q0 & 15));
            const bf16x8 qf = ld8(qbuf + (long)gr_q * 192 + head * 32 + quad * 8);
            const bf16* bbase = biast + ((long)(head * 16 + qg) * 36) * 256 + lane * 4;

            {
                int gy = wi * 16 + aa - 4, gx = wj * 16 + w0 - 4;
                bf16x8 st = zero8();
                if ((unsigned)gy < 64u && (unsigned)gx < 64u) {
                    long gr = (long)(bb * 4096 + gy * 64 + gx) * 384;
                    st = ld8(kvbuf + gr + (isV ? 192 : 0) + head * 32 + dq * 8);
                }
                if (!isV) {
                    *reinterpret_cast<bf16x8*>(&Kc[0][tloc][dq * 8]) = st;
                } else {
#pragma unroll
                    for (int j = 0; j < 8; ++j) Vt[0][dq * 8 + j][tloc] = st[j];
                }
            }
            __syncthreads();

            f32x4 o[2];
            float m_run = -1e30f, l_run = 0.f;
#pragma unroll
            for (int n2 = 0; n2 < 2; ++n2)
#pragma unroll
                for (int r = 0; r < 4; ++r) o[n2][r] = 0.f;

            for (int c = 0; c < 9; ++c) {
                const int cur = c & 1;

                bf16x8 stage;
                if (c < 8) {
                    w0 += 16; aa += 2;
                    if (w0 >= 24) { w0 -= 24; ++aa; }
                    int gy = wi * 16 + aa - 4, gx = wj * 16 + w0 - 4;
                    stage = zero8();
                    if ((unsigned)gy < 64u && (unsigned)gx < 64u) {
                        long gr = (long)(bb * 4096 + gy * 64 + gx) * 384;
                        stage = ld8(kvbuf + gr + (isV ? 192 : 0) + head * 32 + dq * 8);
                    }
                }

                f32x4 s[4];
#pragma unroll
                for (int kt = 0; kt < 4; ++kt) {
                    bf16x8 kf = ld8(&Kc[cur][kt * 16 + llo][quad * 8]);
                    f32x4 zc;
                    zc[0] = 0.f; zc[1] = 0.f; zc[2] = 0.f; zc[3] = 0.f;
                    s[kt] = MFMA16(kf, qf, zc);
                }

#pragma unroll
                for (int kt = 0; kt < 4; ++kt) {
                    bf16x4 bv = ld4(bbase + (c * 4 + kt) * 256);
#pragma unroll
                    for (int r = 0; r < 4; ++r) s[kt][r] += (float)bv[r];
                }

                float mx = s[0][0];
#pragma unroll
                for (int kt = 0; kt < 4; ++kt)
#pragma unroll
                    for (int r = 0; r < 4; ++r) mx = fmaxf(mx, s[kt][r]);
                mx = fmaxf(mx, __shfl_xor(mx, 16));
                mx = fmaxf(mx, __shfl_xor(mx, 32));
                float m_new = fmaxf(m_run, mx);
                float alpha = __expf(m_run - m_new);
                float ls = 0.f;
#pragma unroll
                for (int kt = 0; kt < 4; ++kt)
#pragma unroll
                    for (int r = 0; r < 4; ++r) {
                        float p = __expf(s[kt][r] - m_new);
                        s[kt][r] = p;
                        ls += p;
                    }
                ls += __shfl_xor(ls, 16);
                ls += __shfl_xor(ls, 32);
                l_run = l_run * alpha + ls;
                m_run = m_new;

#pragma unroll
                for (int r = 0; r < 4; ++r) {
                    float a = __shfl(alpha, quad * 4 + r);
                    o[0][r] *= a;
                    o[1][r] *= a;
                }

#pragma unroll
                for (int kt = 0; kt < 4; ++kt) {
                    bf16x4 pv;
#pragma unroll
                    for (int r = 0; r < 4; ++r) pv[r] = (bf16)s[kt][r];
                    *reinterpret_cast<bf16x4*>(&Ps[wave][llo][kt * 16 + quad * 4]) = pv;
                }

#pragma unroll
                for (int kt2 = 0; kt2 < 2; ++kt2) {
                    bf16x8 pa = ld8(&Ps[wave][llo][kt2 * 32 + quad * 8]);
#pragma unroll
                    for (int n2 = 0; n2 < 2; ++n2) {
                        bf16x8 vb = ld8_b32(&Vt[cur][n2 * 16 + llo][kt2 * 32 + quad * 8]);
                        o[n2] = MFMA16(pa, vb, o[n2]);
                    }
                }

                if (c < 8) {
                    if (!isV) {
                        *reinterpret_cast<bf16x8*>(&Kc[1 - cur][tloc][dq * 8]) = stage;
                    } else {
#pragma unroll
                        for (int j = 0; j < 8; ++j) Vt[1 - cur][dq * 8 + j][tloc] = stage[j];
                    }
                    __syncthreads();
                }
            }

            float linv = 1.f / l_run;
#pragma unroll
            for (int r = 0; r < 4; ++r) {
                float li = __shfl(linv, quad * 4 + r);
                int q = qbase + quad * 4 + r;
                int gr = bb * 4096 + (wi * 16 + (q >> 4)) * 64 + (wj * 16 + (q & 15));
#pragma unroll
                for (int n2 = 0; n2 < 2; ++n2)
                    obuf[(long)gr * 192 + head * 32 + n2 * 16 + llo] = (bf16)(o[n2][r] * li);
            }
        }
    }
    gridbar(bars + 2);

    // ================= P3: proj + bias + residual + LN2 ====================
    {
        bf16* Sa = (bf16*)SM;             // 64*200
        bf16* Sb = (bf16*)(SM + 25600);   // 96*200
        float* Pr = (float*)(SM + 64000); // [64][2][2]
        const int rt = wave >> 1, ch = wave & 1;
        const int mbase = blk * 64;

        stage_tile<64, 192, 192, 512>(obuf + (long)mbase * 192, Sa, tid);
        bf16x8 wreg[5];
        load_chunk_g<96, 192, 192, 512>(wproj, wreg, tid);

        f32x4 acc[6];
#pragma unroll
        for (int t6 = 0; t6 < 6; ++t6)
#pragma unroll
            for (int r = 0; r < 4; ++r) acc[t6][r] = 0.f;

        for (int nc = 0; nc < 2; ++nc) {
            if (nc) __syncthreads();
            store_chunk_l<96, 192, 512>(Sb, wreg, tid);
            __syncthreads();
            if (nc == 0) load_chunk_g<96, 192, 192, 512>(wproj + 96L * 192, wreg, tid);
#pragma unroll
            for (int kt = 0; kt < 6; ++kt) {
                bf16x8 a = ld8(Sa + (rt * 16 + llo) * 200 + kt * 32 + quad * 8);
#pragma unroll
                for (int ctl = 0; ctl < 3; ++ctl) {
                    bf16x8 b = ld8(Sb + (ch * 48 + ctl * 16 + llo) * 200 + kt * 32 + quad * 8);
                    acc[nc * 3 + ctl] = MFMA16(a, b, acc[nc * 3 + ctl]);
                }
            }
        }

        float v[4][6];
#pragma unroll
        for (int r = 0; r < 4; ++r) {
            float sum = 0.f, sq = 0.f;
#pragma unroll
            for (int t6 = 0; t6 < 6; ++t6) {
                int n = (t6 / 3) * 96 + ch * 48 + (t6 % 3) * 16 + llo;
                float val = 0.f;
                if (n < 180) {
                    int m = mbase + rt * 16 + quad * 4 + r;
                    val = acc[t6][r] + proj_b[n] + x[(long)m * 180 + n];
                }
                v[r][t6] = val;
                sum += val; sq += val * val;
            }
#pragma unroll
            for (int msk = 1; msk <= 8; msk <<= 1) {
                sum += __shfl_xor(sum, msk);
                sq  += __shfl_xor(sq, msk);
            }
            if (llo == 0) {
                int rl = rt * 16 + quad * 4 + r;
                Pr[rl * 4 + ch * 2] = sum;
                Pr[rl * 4 + ch * 2 + 1] = sq;
            }
        }
        __syncthreads();
#pragma unroll
        for (int r = 0; r < 4; ++r) {
            int rl = rt * 16 + quad * 4 + r;
            float sum = Pr[rl * 4] + Pr[rl * 4 + 2];
            float sq  = Pr[rl * 4 + 1] + Pr[rl * 4 + 3];
            float mean = sum * (1.f / 180.f);
            float var = sq * (1.f / 180.f) - mean * mean;
            float rs = rsqrtf(var + 1e-5f);
            int m = mbase + rl;
#pragma unroll
            for (int t6 = 0; t6 < 6; ++t6) {
                int n = (t6 / 3) * 96 + ch * 48 + (t6 % 3) * 16 + llo;
                if (n < 180) {
                    xo[(long)m * 180 + n] = v[r][t6];
                    xn2[(long)m * 192 + n] = (bf16)((v[r][t6] - mean) * rs * n2g[n] + n2b[n]);
                } else {
                    xn2[(long)m * 192 + n] = (bf16)0.f;
                }
            }
        }
    }
    gridbar(bars + 3);

    // ================= P4: fc1 + gelu ======================================
    {
        bf16* Sa = (bf16*)SM;             // 128*200
        bf16* Sb = (bf16*)(SM + 51200);   // 64*200
        const int tmi = blk >> 1;
        const int tm = tmi * 128;
        stage_tile<128, 192, 192, 512>(xn2 + (long)tm * 192, Sa, tid);
        for (int zz = 0; zz < 2; ++zz) {
            const int bz = (blk & 1) * 2 + zz;
            const bf16* Wbase = wfc1 + (long)bz * 3 * 64 * 192;
            bf16x8 wreg[3];
            load_chunk_g<64, 192, 192, 512>(Wbase, wreg, tid);
            for (int s = 0; s < 3; ++s) {
                if (s || zz) __syncthreads();
                store_chunk_l<64, 192, 512>(Sb, wreg, tid);
                __syncthreads();
                if (s < 2) load_chunk_g<64, 192, 192, 512>(Wbase + (long)(s + 1) * 64 * 192, wreg, tid);

                f32x4 acc[4];
#pragma unroll
                for (int nt = 0; nt < 4; ++nt)
#pragma unroll
                    for (int r = 0; r < 4; ++r) acc[nt][r] = 0.f;
#pragma unroll
                for (int kt = 0; kt < 6; ++kt) {
                    bf16x8 a = ld8(Sa + (wave * 16 + llo) * 200 + kt * 32 + quad * 8);
#pragma unroll
                    for (int nt = 0; nt < 4; ++nt) {
                        bf16x8 b = ld8(Sb + (nt * 16 + llo) * 200 + kt * 32 + quad * 8);
                        acc[nt] = MFMA16(a, b, acc[nt]);
                    }
                }

                const int nb = (bz * 3 + s) * 64;
#pragma unroll
                for (int nt = 0; nt < 4; ++nt) {
                    int n = nb + nt * 16 + llo;
                    if (n >= 720) continue;
                    float bv = fc1_b[n];
#pragma unroll
                    for (int r = 0; r < 4; ++r) {
                        int m = tm + wave * 16 + quad * 4 + r;
                        float vv = acc[nt][r] + bv;
                        float gel = 0.5f * vv * (1.f + erff(vv * 0.7071067811865475f));
                        hmid[(long)m * 736 + n] = (bf16)gel;
                    }
                }
            }
        }
    }
    gridbar(bars + 4);

    // ================= P5: fc2 + residual ==================================
    {
        bf16* Sa = (bf16*)SM;             // 64*200
        bf16* Sb = (bf16*)(SM + 25600);   // 64*200
        const int rt = wave >> 1, chn = wave & 1;
        const int tm = blk * 64;
        const bf16* Ap = hmid + (long)tm * 736;
        for (int tni = 0; tni < 3; ++tni) {
            const int tn = tni * 64;
            const bf16* Wp = wfc2 + (long)tn * 736;
            bf16x8 ar[3], wr[3];
            load_chunk_g<64, 192, 736, 512>(Ap, ar, tid);
            load_chunk_g<64, 192, 736, 512>(Wp, wr, tid);

            f32x4 acc[2];
#pragma unroll
            for (int j = 0; j < 2; ++j)
#pragma unroll
                for (int r = 0; r < 4; ++r) acc[j][r] = 0.f;

#pragma unroll
            for (int c = 0; c < 4; ++c) {
                if (c || tni) __syncthreads();
                if (c < 3) {
                    store_chunk_l<64, 192, 512>(Sa, ar, tid);
                    store_chunk_l<64, 192, 512>(Sb, wr, tid);
                } else {
                    store_chunk_l<64, 160, 512>(Sa, ar, tid);
                    store_chunk_l<64, 160, 512>(Sb, wr, tid);
                }
                __syncthreads();
                if (c < 2) {
                    load_chunk_g<64, 192, 736, 512>(Ap + (c + 1) * 192, ar, tid);
                    load_chunk_g<64, 192, 736, 512>(Wp + (c + 1) * 192, wr, tid);
                } else if (c == 2) {
                    load_chunk_g<64, 160, 736, 512>(Ap + 576, ar, tid);
                    load_chunk_g<64, 160, 736, 512>(Wp + 576, wr, tid);
                }
                const int nkt = (c == 3) ? 5 : 6;
                for (int kt = 0; kt < nkt; ++kt) {
                    bf16x8 a = ld8(Sa + (rt * 16 + llo) * 200 + kt * 32 + quad * 8);
#pragma unroll
                    for (int j = 0; j < 2; ++j) {
                        bf16x8 b = ld8(Sb + ((chn * 2 + j) * 16 + llo) * 200 + kt * 32 + quad * 8);
                        acc[j] = MFMA16(a, b, acc[j]);
                    }
                }
            }

#pragma unroll
            for (int j = 0; j < 2; ++j)
#pragma unroll
                for (int r = 0; r < 4; ++r) {
                    int m = tm + rt * 16 + quad * 4 + r;
                    int n = tn + (chn * 2 + j) * 16 + llo;
                    if (n >= 180) continue;
                    float vv = acc[j][r] + fc2_b[n];
                    outp[(long)m * 180 + n] = vv + xo[(long)m * 180 + n];
                }
        }
    }
}

// ---------------------------------------------------------------------------
extern "C" void kernel_launch(void* const* d_in, const int* in_sizes, int n_in,
                              void* d_out, int out_size, void* d_ws, size_t ws_size,
                              hipStream_t stream) {
    const float* x      = (const float*)d_in[0];
    const float* y      = (const float*)d_in[1];
    const float* n1g    = (const float*)d_in[2];
    const float* n1b    = (const float*)d_in[3];
    const float* kv_w   = (const float*)d_in[4];
    const float* kv_b   = (const float*)d_in[5];
    const float* q_w    = (const float*)d_in[6];
    const float* q_b    = (const float*)d_in[7];
    const float* rpb    = (const float*)d_in[8];
    const float* proj_w = (const float*)d_in[9];
    const float* proj_b = (const float*)d_in[10];
    const float* n2g    = (const float*)d_in[11];
    const float* n2b    = (const float*)d_in[12];
    const float* fc1_w  = (const float*)d_in[13];
    const float* fc1_b  = (const float*)d_in[14];
    const float* fc2_w  = (const float*)d_in[15];
    const float* fc2_b  = (const float*)d_in[16];
    const int*   rpi    = (const int*)d_in[17];

    char* ws = (char*)d_ws;
    bf16* xn    = (bf16*)(ws + 0);          // [16384][192]
    bf16* yn    = (bf16*)(ws + 6291456);    // [16384][192]
    bf16* qbuf  = (bf16*)(ws + 12582912);   // [16384][192]
    bf16* kvbuf = (bf16*)(ws + 18874368);   // [16384][384]
    bf16* obuf  = (bf16*)(ws + 31457280);   // [16384][192]
    float* xo   = (float*)(ws + 37748736);  // [16384][180] fp32
    bf16* biast = (bf16*)(ws + 49545216);   // [6][16][36][64][4]
    bf16* wkv   = (bf16*)(ws + 51314688);
    bf16* wq    = (bf16*)(ws + 51462144);
    bf16* wproj = (bf16*)(ws + 51560448);
    bf16* wfc1  = (bf16*)(ws + 51658752);
    bf16* wfc2  = (bf16*)(ws + 51953664);
    bf16* hmid  = (bf16*)(ws + 6291456);    // reuse yn/qbuf/kvbuf (dead post-attn)
    bf16* xn2   = xn;                       // xn dead after P1
    unsigned* bars = (unsigned*)(ws + 52428800);

    hipMemsetAsync(ws + 52428800, 0, 64, stream);
    mega<<<NBLK, 512, 0, stream>>>(x, y, n1g, n1b, kv_w, kv_b, q_w, q_b, rpb, rpi,
                                   proj_w, proj_b, n2g, n2b, fc1_w, fc1_b, fc2_w, fc2_b,
                                   xn, yn, qbuf, kvbuf, obuf, xo, biast,
                                   wkv, wq, wproj, wfc1, wfc2, hmid, xn2,
                                   (float*)d_out, bars);
}

// Round 5
// 198.200 us; speedup vs baseline: 3.5542x; 3.5542x over previous
//
#include <hip/hip_runtime.h>

typedef __bf16 bf16;
typedef __bf16 bf16x8 __attribute__((ext_vector_type(8)));
typedef __bf16 bf16x4 __attribute__((ext_vector_type(4)));
typedef __bf16 bf16x2 __attribute__((ext_vector_type(2)));
typedef float f32x4 __attribute__((ext_vector_type(4)));

static __device__ __forceinline__ bf16x8 ld8(const bf16* p) {
    return *reinterpret_cast<const bf16x8*>(p);
}
static __device__ __forceinline__ bf16x4 ld4(const bf16* p) {
    return *reinterpret_cast<const bf16x4*>(p);
}
static __device__ __forceinline__ bf16x8 ld8_b32(const bf16* p) {
    bf16x8 v;
#pragma unroll
    for (int i = 0; i < 4; ++i) {
        bf16x2 t = *reinterpret_cast<const bf16x2*>(p + i * 2);
        v[i * 2] = t[0]; v[i * 2 + 1] = t[1];
    }
    return v;
}
static __device__ __forceinline__ bf16x8 zero8() {
    bf16x8 v;
#pragma unroll
    for (int i = 0; i < 8; ++i) v[i] = (bf16)0.f;
    return v;
}

#define MFMA16(a, b, c) __builtin_amdgcn_mfma_f32_16x16x32_bf16((a), (b), (c), 0, 0, 0)

// Generic tile movers. LDS row stride fixed at 200 elems (conflict-free for
// both the b128 staging stores and the fragment ds_read_b128s).
template <int ROWS, int BK, int KPAD, int THREADS>
static __device__ __forceinline__ void load_chunk_g(const bf16* __restrict__ g,
                                                    bf16x8* r, int tid) {
    constexpr int TOT = ROWS * BK / 8;
    constexpr int NP = (TOT + THREADS - 1) / THREADS;
#pragma unroll
    for (int p = 0; p < NP; ++p) {
        int idx = p * THREADS + tid;
        if ((TOT % THREADS) == 0 || idx < TOT) {
            int row = idx / (BK / 8), cg = idx % (BK / 8);
            r[p] = ld8(g + (long)row * KPAD + cg * 8);
        }
    }
}
template <int ROWS, int BK, int THREADS>
static __device__ __forceinline__ void store_chunk_l(bf16* __restrict__ lds,
                                                     const bf16x8* r, int tid) {
    constexpr int TOT = ROWS * BK / 8;
    constexpr int NP = (TOT + THREADS - 1) / THREADS;
#pragma unroll
    for (int p = 0; p < NP; ++p) {
        int idx = p * THREADS + tid;
        if ((TOT % THREADS) == 0 || idx < TOT) {
            int row = idx / (BK / 8), cg = idx % (BK / 8);
            *reinterpret_cast<bf16x8*>(lds + row * 200 + cg * 8) = r[p];
        }
    }
}
template <int ROWS, int BK, int KPAD, int THREADS>
static __device__ __forceinline__ void stage_tile(const bf16* __restrict__ g,
                                                  bf16* __restrict__ lds, int tid) {
    constexpr int TOT = ROWS * BK / 8;
    constexpr int NP = (TOT + THREADS - 1) / THREADS;
#pragma unroll
    for (int p = 0; p < NP; ++p) {
        int idx = p * THREADS + tid;
        if ((TOT % THREADS) == 0 || idx < TOT) {
            int row = idx / (BK / 8), cg = idx % (BK / 8);
            bf16x8 v = ld8(g + (long)row * KPAD + cg * 8);
            *reinterpret_cast<bf16x8*>(lds + row * 200 + cg * 8) = v;
        }
    }
}

// ---------------------------------------------------------------------------
// fused_pre v2: 1704 blocks, each grid-strides over 8 of the original
// 13632 block-units (unit < 8192: LayerNorm of 4 rows; else weight conv +
// bias-table gather). Same per-unit code as before — only dispatch count
// changed (13632 -> 1704) to cut workgroup launch/ramp overhead (G11).
// ---------------------------------------------------------------------------
__global__ __launch_bounds__(256) void fused_pre(
    const float* __restrict__ x, const float* __restrict__ y,
    const float* __restrict__ g, const float* __restrict__ b,
    bf16* __restrict__ dst,
    const float* __restrict__ kv_w, const float* __restrict__ q_w,
    const float* __restrict__ proj_w, const float* __restrict__ fc1_w,
    const float* __restrict__ fc2_w, const float* __restrict__ rpb,
    const int* __restrict__ rpi,
    bf16* __restrict__ wkv, bf16* __restrict__ wq, bf16* __restrict__ wproj,
    bf16* __restrict__ wfc1, bf16* __restrict__ wfc2, bf16* __restrict__ biast)
{
    for (int u = blockIdx.x; u < 13632; u += 1704) {
        if (u < 8192) {
            int wave = threadIdx.x >> 6, lane = threadIdx.x & 63;
            int row = u * 4 + wave;
            const float* sp = (row < 16384) ? (x + (long)row * 180)
                                            : (y + (long)(row - 16384) * 180);
            float v0 = sp[lane];
            float v1 = sp[lane + 64];
            float v2 = (lane < 52) ? sp[lane + 128] : 0.f;
            float s = v0 + v1 + v2;
            float sq = v0 * v0 + v1 * v1 + v2 * v2;
#pragma unroll
            for (int m = 32; m >= 1; m >>= 1) {
                s += __shfl_xor(s, m);
                sq += __shfl_xor(sq, m);
            }
            float mean = s * (1.f / 180.f);
            float var = sq * (1.f / 180.f) - mean * mean;
            float rs = rsqrtf(var + 1e-5f);
            bf16* dp = dst + (long)row * 192;
            dp[lane] = (bf16)((v0 - mean) * rs * g[lane] + b[lane]);
            dp[lane + 64] = (bf16)((v1 - mean) * rs * g[lane + 64] + b[lane + 64]);
            float o2 = (lane < 52) ? ((v2 - mean) * rs * g[lane + 128] + b[lane + 128]) : 0.f;
            dp[lane + 128] = (bf16)o2;
            continue;
        }
        int i = (u - 8192) * 256 + threadIdx.x;
        if (i < 73728) {                       // wkv
            int n = i / 192, k = i % 192;
            float v = (n < 360 && k < 180) ? kv_w[n * 180 + k] : 0.f;
            wkv[i] = (bf16)v;
        } else if (i < 122880) {               // wq
            int j = i - 73728; int n = j / 192, k = j % 192;
            float v = (n < 180 && k < 180) ? q_w[n * 180 + k] : 0.f;
            wq[j] = (bf16)v;
        } else if (i < 172032) {               // wproj (head-padded K)
            int j = i - 122880; int n = j / 192, k = j % 192;
            int hh = k >> 5, d = k & 31;
            float v = (n < 180 && d < 30) ? proj_w[n * 180 + hh * 30 + d] : 0.f;
            wproj[j] = (bf16)v;
        } else if (i < 319488) {               // wfc1
            int j = i - 172032; int n = j / 192, k = j % 192;
            float v = (n < 720 && k < 180) ? fc1_w[n * 180 + k] : 0.f;
            wfc1[j] = (bf16)v;
        } else if (i < 507904) {               // wfc2
            int j = i - 319488; int n = j / 736, k = j % 736;
            float v = (n < 180 && k < 720) ? fc2_w[n * 720 + k] : 0.f;
            wfc2[j] = (bf16)v;
        } else if (i < 1392640) {              // bias table, frag-coalesced
            int t = i - 507904;
            int r = t & 3;
            int lane = (t >> 2) & 63;
            int tmp2 = t >> 8;
            int kg = tmp2 % 36;
            int tmp3 = tmp2 / 36;
            int qg = tmp3 & 15;
            int h = tmp3 >> 4;
            int q = qg * 16 + (lane & 15);
            int key = kg * 16 + ((lane >> 4) << 2) + r;
            biast[t] = (bf16)rpb[rpi[q * 576 + key] * 6 + h];
        }
    }
}

// ---------------------------------------------------------------------------
// kv+q projection (round-0 128-row structure) + XCD swizzle:
// 384 blocks = 8 XCD x (16 tm x 3 bz). bz=0,1 share the xn A-tile; grouping
// them on one XCD makes the second read an L2 hit.
// ---------------------------------------------------------------------------
__global__ __launch_bounds__(512, 4) void gemm_kvq(
    const bf16* __restrict__ xn, const bf16* __restrict__ yn,
    const bf16* __restrict__ wkv, const bf16* __restrict__ wq,
    const float* __restrict__ kv_b, const float* __restrict__ q_b,
    bf16* __restrict__ kvbuf, bf16* __restrict__ qbuf)
{
    const int tid = threadIdx.x, wave = tid >> 6, lane = tid & 63;
    const int llo = lane & 15, quad = lane >> 4;
    const int phys = blockIdx.x;
    const int xcd = phys & 7, idx = phys >> 3;     // idx 0..47
    const int tmi = xcd * 16 + idx / 3;            // 0..127
    const int bz = idx % 3;
    const bool isq = (bz == 2);
    const bf16* A = isq ? yn : xn;
    const bf16* Wbase = isq ? wq : (wkv + (long)bz * 3 * 64 * 192);
    const int tm = tmi * 128;

    __shared__ __align__(16) bf16 Sa[128 * 200];
    __shared__ __align__(16) bf16 Sb[64 * 200];

    stage_tile<128, 192, 192, 512>(A + (long)tm * 192, Sa, tid);
    bf16x8 wreg[3];
    load_chunk_g<64, 192, 192, 512>(Wbase, wreg, tid);

    for (int s = 0; s < 3; ++s) {
        if (s) __syncthreads();
        store_chunk_l<64, 192, 512>(Sb, wreg, tid);
        __syncthreads();
        if (s < 2) load_chunk_g<64, 192, 192, 512>(Wbase + (long)(s + 1) * 64 * 192, wreg, tid);

        f32x4 acc[4];
#pragma unroll
        for (int nt = 0; nt < 4; ++nt)
#pragma unroll
            for (int r = 0; r < 4; ++r) acc[nt][r] = 0.f;
#pragma unroll
        for (int kt = 0; kt < 6; ++kt) {
            bf16x8 a = ld8(Sa + (wave * 16 + llo) * 200 + kt * 32 + quad * 8);
#pragma unroll
            for (int nt = 0; nt < 4; ++nt) {
                bf16x8 b = ld8(Sb + (nt * 16 + llo) * 200 + kt * 32 + quad * 8);
                acc[nt] = MFMA16(a, b, acc[nt]);
            }
        }

        const int g = bz * 3 + s;
#pragma unroll
        for (int nt = 0; nt < 4; ++nt) {
            int n = g * 64 + nt * 16 + llo;
            if (!isq) {
                if (n < 360) {
                    int nn = n % 180;
                    int col = (n / 180) * 192 + (nn / 30) * 32 + (nn % 30);
                    float bv = kv_b[n];
#pragma unroll
                    for (int r = 0; r < 4; ++r) {
                        int m = tm + wave * 16 + quad * 4 + r;
                        kvbuf[(long)m * 384 + col] = (bf16)(acc[nt][r] + bv);
                    }
                }
            } else {
                int nq = n - 384;
                if (nq < 180) {
                    int col = (nq / 30) * 32 + (nq % 30);
                    float bv = q_b[nq];
#pragma unroll
                    for (int r = 0; r < 4; ++r) {
                        int m = tm + wave * 16 + quad * 4 + r;
                        qbuf[(long)m * 192 + col] =
                            (bf16)((acc[nt][r] + bv) * 0.18257418583505537f);
                    }
                }
            }
        }
    }
}

// ---------------------------------------------------------------------------
// Attention v8: v7 + XCD swizzle. 768 blocks = 8 XCD x (8 win x 12 sub);
// the 12 (head,qhalf) blocks of one window share its K/V slice —
// grouping them per-XCD turns the 12x kvbuf read into L2 hits.
// ---------------------------------------------------------------------------
__global__ __launch_bounds__(512, 6) void attn_kernel(
    const bf16* __restrict__ qbuf, const bf16* __restrict__ kvbuf,
    const bf16* __restrict__ biast, bf16* __restrict__ obuf)
{
    const int phys = blockIdx.x;
    const int xcd = phys & 7, idx = phys >> 3;     // idx 0..95
    const int win = xcd * 8 + idx / 12;            // 0..63
    const int sub = idx % 12;
    const int qhalf = sub & 1;
    const int head = sub >> 1;
    const int bb = win / 16, wi = (win % 16) / 4, wj = win % 4;
    const int tid = threadIdx.x;
    const int wave = tid >> 6, lane = tid & 63;
    const int llo = lane & 15, quad = lane >> 4;
    const int qbase = qhalf * 128 + wave * 16;
    const int qg = qhalf * 8 + wave;

    __shared__ bf16 Kc[2][64][40];
    __shared__ bf16 Vt[2][32][74];
    __shared__ bf16 Ps[8][16][72];

    const int u = tid & 255;
    const int tloc = u >> 2, dq = u & 3;
    const bool isV = tid >= 256;
    int aa = tloc / 24, w0 = tloc % 24;

    const int q0 = qbase + llo;
    const int gr_q = bb * 4096 + (wi * 16 + (q0 >> 4)) * 64 + (wj * 16 + (q0 & 15));
    const bf16x8 qf = ld8(qbuf + (long)gr_q * 192 + head * 32 + quad * 8);
    const bf16* bbase = biast + ((long)(head * 16 + qg) * 36) * 256 + lane * 4;

    {
        int gy = wi * 16 + aa - 4, gx = wj * 16 + w0 - 4;
        bf16x8 st = zero8();
        if ((unsigned)gy < 64u && (unsigned)gx < 64u) {
            long gr = (long)(bb * 4096 + gy * 64 + gx) * 384;
            st = ld8(kvbuf + gr + (isV ? 192 : 0) + head * 32 + dq * 8);
        }
        if (!isV) {
            *reinterpret_cast<bf16x8*>(&Kc[0][tloc][dq * 8]) = st;
        } else {
#pragma unroll
            for (int j = 0; j < 8; ++j) Vt[0][dq * 8 + j][tloc] = st[j];
        }
    }
    __syncthreads();

    f32x4 o[2];
    float m_run = -1e30f, l_run = 0.f;
#pragma unroll
    for (int n2 = 0; n2 < 2; ++n2)
#pragma unroll
        for (int r = 0; r < 4; ++r) o[n2][r] = 0.f;

    for (int c = 0; c < 9; ++c) {
        const int cur = c & 1;

        bf16x8 stage;
        if (c < 8) {
            w0 += 16; aa += 2;
            if (w0 >= 24) { w0 -= 24; ++aa; }
            int gy = wi * 16 + aa - 4, gx = wj * 16 + w0 - 4;
            stage = zero8();
            if ((unsigned)gy < 64u && (unsigned)gx < 64u) {
                long gr = (long)(bb * 4096 + gy * 64 + gx) * 384;
                stage = ld8(kvbuf + gr + (isV ? 192 : 0) + head * 32 + dq * 8);
            }
        }

        f32x4 s[4];
#pragma unroll
        for (int kt = 0; kt < 4; ++kt) {
            bf16x8 kf = ld8(&Kc[cur][kt * 16 + llo][quad * 8]);
            f32x4 zc;
            zc[0] = 0.f; zc[1] = 0.f; zc[2] = 0.f; zc[3] = 0.f;
            s[kt] = MFMA16(kf, qf, zc);
        }

#pragma unroll
        for (int kt = 0; kt < 4; ++kt) {
            bf16x4 bv = ld4(bbase + (c * 4 + kt) * 256);
#pragma unroll
            for (int r = 0; r < 4; ++r) s[kt][r] += (float)bv[r];
        }

        float mx = s[0][0];
#pragma unroll
        for (int kt = 0; kt < 4; ++kt)
#pragma unroll
            for (int r = 0; r < 4; ++r) mx = fmaxf(mx, s[kt][r]);
        mx = fmaxf(mx, __shfl_xor(mx, 16));
        mx = fmaxf(mx, __shfl_xor(mx, 32));
        float m_new = fmaxf(m_run, mx);
        float alpha = __expf(m_run - m_new);
        float ls = 0.f;
#pragma unroll
        for (int kt = 0; kt < 4; ++kt)
#pragma unroll
            for (int r = 0; r < 4; ++r) {
                float p = __expf(s[kt][r] - m_new);
                s[kt][r] = p;
                ls += p;
            }
        ls += __shfl_xor(ls, 16);
        ls += __shfl_xor(ls, 32);
        l_run = l_run * alpha + ls;
        m_run = m_new;

#pragma unroll
        for (int r = 0; r < 4; ++r) {
            float a = __shfl(alpha, quad * 4 + r);
            o[0][r] *= a;
            o[1][r] *= a;
        }

#pragma unroll
        for (int kt = 0; kt < 4; ++kt) {
            bf16x4 pv;
#pragma unroll
            for (int r = 0; r < 4; ++r) pv[r] = (bf16)s[kt][r];
            *reinterpret_cast<bf16x4*>(&Ps[wave][llo][kt * 16 + quad * 4]) = pv;
        }

#pragma unroll
        for (int kt2 = 0; kt2 < 2; ++kt2) {
            bf16x8 pa = ld8(&Ps[wave][llo][kt2 * 32 + quad * 8]);
#pragma unroll
            for (int n2 = 0; n2 < 2; ++n2) {
                bf16x8 vb = ld8_b32(&Vt[cur][n2 * 16 + llo][kt2 * 32 + quad * 8]);
                o[n2] = MFMA16(pa, vb, o[n2]);
            }
        }

        if (c < 8) {
            if (!isV) {
                *reinterpret_cast<bf16x8*>(&Kc[1 - cur][tloc][dq * 8]) = stage;
            } else {
#pragma unroll
                for (int j = 0; j < 8; ++j) Vt[1 - cur][dq * 8 + j][tloc] = stage[j];
            }
            __syncthreads();
        }
    }

    float linv = 1.f / l_run;
#pragma unroll
    for (int r = 0; r < 4; ++r) {
        float li = __shfl(linv, quad * 4 + r);
        int q = qbase + quad * 4 + r;
        int gr = bb * 4096 + (wi * 16 + (q >> 4)) * 64 + (wj * 16 + (q & 15));
#pragma unroll
        for (int n2 = 0; n2 < 2; ++n2)
            obuf[(long)gr * 192 + head * 32 + n2 * 16 + llo] = (bf16)(o[n2][r] * li);
    }
}

// ---------------------------------------------------------------------------
// Fused proj + bias + residual + LN2 (unchanged structure).
// ---------------------------------------------------------------------------
__global__ __launch_bounds__(256, 3) void gemm_projln(
    const bf16* __restrict__ obuf, const bf16* __restrict__ wproj,
    const float* __restrict__ proj_b, const float* __restrict__ x,
    const float* __restrict__ g, const float* __restrict__ bln,
    float* __restrict__ xo, bf16* __restrict__ xn2)
{
    const int tid = threadIdx.x, wave = tid >> 6, lane = tid & 63;
    const int llo = lane & 15, quad = lane >> 4;
    const int mbase = blockIdx.x * 64;

    __shared__ __align__(16) bf16 Sa[64 * 200];
    __shared__ __align__(16) bf16 Sb[64 * 200];
    stage_tile<64, 192, 192, 256>(obuf + (long)mbase * 192, Sa, tid);
    bf16x8 wreg[6];
    load_chunk_g<64, 192, 192, 256>(wproj, wreg, tid);

    f32x4 acc[12];
#pragma unroll
    for (int nt = 0; nt < 12; ++nt)
#pragma unroll
        for (int r = 0; r < 4; ++r) acc[nt][r] = 0.f;

    for (int nc = 0; nc < 3; ++nc) {
        if (nc) __syncthreads();
        store_chunk_l<64, 192, 256>(Sb, wreg, tid);
        __syncthreads();
        if (nc < 2) load_chunk_g<64, 192, 192, 256>(wproj + (long)(nc + 1) * 64 * 192, wreg, tid);
#pragma unroll
        for (int kt = 0; kt < 6; ++kt) {
            bf16x8 a = ld8(Sa + (wave * 16 + llo) * 200 + kt * 32 + quad * 8);
#pragma unroll
            for (int nt = 0; nt < 4; ++nt) {
                bf16x8 b = ld8(Sb + (nt * 16 + llo) * 200 + kt * 32 + quad * 8);
                acc[nc * 4 + nt] = MFMA16(a, b, acc[nc * 4 + nt]);
            }
        }
    }

#pragma unroll
    for (int r = 0; r < 4; ++r) {
        int m = mbase + wave * 16 + quad * 4 + r;
        float v[12];
        float sum = 0.f, sq = 0.f;
#pragma unroll
        for (int nt = 0; nt < 12; ++nt) {
            int n = nt * 16 + llo;
            float val = 0.f;
            if (n < 180) val = acc[nt][r] + proj_b[n] + x[(long)m * 180 + n];
            v[nt] = val;
            sum += val; sq += val * val;
        }
#pragma unroll
        for (int msk = 1; msk <= 8; msk <<= 1) {
            sum += __shfl_xor(sum, msk);
            sq  += __shfl_xor(sq, msk);
        }
        float mean = sum * (1.f / 180.f);
        float var = sq * (1.f / 180.f) - mean * mean;
        float rs = rsqrtf(var + 1e-5f);
#pragma unroll
        for (int nt = 0; nt < 12; ++nt) {
            int n = nt * 16 + llo;
            if (n < 180) {
                xo[(long)m * 180 + n] = v[nt];
                xn2[(long)m * 192 + n] = (bf16)((v[nt] - mean) * rs * g[n] + bln[n]);
            } else {
                xn2[(long)m * 192 + n] = (bf16)0.f;
            }
        }
    }
}

// ---------------------------------------------------------------------------
// fc1 (round-0 128-row structure) + XCD swizzle:
// 512 blocks = 8 XCD x (16 tm x 4 bz); the 4 bz share the A-tile.
// ---------------------------------------------------------------------------
__global__ __launch_bounds__(512, 4) void gemm_fc1(
    const bf16* __restrict__ A, const bf16* __restrict__ W,
    const float* __restrict__ bias, bf16* __restrict__ outp)
{
    const int tid = threadIdx.x, wave = tid >> 6, lane = tid & 63;
    const int llo = lane & 15, quad = lane >> 4;
    const int phys = blockIdx.x;
    const int xcd = phys & 7, idx = phys >> 3;     // idx 0..63
    const int tmi = xcd * 16 + idx / 4;            // 0..127
    const int bz = idx % 4;
    const int tm = tmi * 128;
    const bf16* Wbase = W + (long)bz * 3 * 64 * 192;

    __shared__ __align__(16) bf16 Sa[128 * 200];
    __shared__ __align__(16) bf16 Sb[64 * 200];
    stage_tile<128, 192, 192, 512>(A + (long)tm * 192, Sa, tid);
    bf16x8 wreg[3];
    load_chunk_g<64, 192, 192, 512>(Wbase, wreg, tid);

    for (int s = 0; s < 3; ++s) {
        if (s) __syncthreads();
        store_chunk_l<64, 192, 512>(Sb, wreg, tid);
        __syncthreads();
        if (s < 2) load_chunk_g<64, 192, 192, 512>(Wbase + (long)(s + 1) * 64 * 192, wreg, tid);

        f32x4 acc[4];
#pragma unroll
        for (int nt = 0; nt < 4; ++nt)
#pragma unroll
            for (int r = 0; r < 4; ++r) acc[nt][r] = 0.f;
#pragma unroll
        for (int kt = 0; kt < 6; ++kt) {
            bf16x8 a = ld8(Sa + (wave * 16 + llo) * 200 + kt * 32 + quad * 8);
#pragma unroll
            for (int nt = 0; nt < 4; ++nt) {
                bf16x8 b = ld8(Sb + (nt * 16 + llo) * 200 + kt * 32 + quad * 8);
                acc[nt] = MFMA16(a, b, acc[nt]);
            }
        }

        const int nb = (bz * 3 + s) * 64;
#pragma unroll
        for (int nt = 0; nt < 4; ++nt) {
            int n = nb + nt * 16 + llo;
            if (n >= 720) continue;
            float bv = bias[n];
#pragma unroll
            for (int r = 0; r < 4; ++r) {
                int m = tm + wave * 16 + quad * 4 + r;
                float v = acc[nt][r] + bv;
                float gel = 0.5f * v * (1.f + erff(v * 0.7071067811865475f));
                outp[(long)m * 736 + n] = (bf16)gel;
            }
        }
    }
}

// ---------------------------------------------------------------------------
// fc2 + XCD swizzle: 768 blocks (1D) = 8 XCD x (32 tm x 3 tn); the 3 tn
// blocks share the 64x736 A-panel -> L2 hits instead of 3x HBM.
// ---------------------------------------------------------------------------
__global__ __launch_bounds__(256, 4) void gemm_fc2(
    const bf16* __restrict__ A, const bf16* __restrict__ W,
    const float* __restrict__ bias, const float* __restrict__ resid,
    float* __restrict__ outp)
{
    const int tid = threadIdx.x, wave = tid >> 6, lane = tid & 63;
    const int llo = lane & 15, quad = lane >> 4;
    const int phys = blockIdx.x;
    const int xcd = phys & 7, idx = phys >> 3;     // idx 0..95
    const int tmi = xcd * 32 + idx / 3;            // 0..255
    const int tni = idx % 3;
    const int tm = tmi * 64;
    const int tn = tni * 64;

    __shared__ __align__(16) bf16 Sa[64 * 200];
    __shared__ __align__(16) bf16 Sb[64 * 200];

    const bf16* Ap = A + (long)tm * 736;
    const bf16* Wp = W + (long)tn * 736;

    bf16x8 ar[6], wr[6];
    load_chunk_g<64, 192, 736, 256>(Ap, ar, tid);
    load_chunk_g<64, 192, 736, 256>(Wp, wr, tid);

    f32x4 acc[4];
#pragma unroll
    for (int nt = 0; nt < 4; ++nt)
#pragma unroll
        for (int r = 0; r < 4; ++r) acc[nt][r] = 0.f;

#pragma unroll
    for (int c = 0; c < 4; ++c) {
        if (c) __syncthreads();
        if (c < 3) {
            store_chunk_l<64, 192, 256>(Sa, ar, tid);
            store_chunk_l<64, 192, 256>(Sb, wr, tid);
        } else {
            store_chunk_l<64, 160, 256>(Sa, ar, tid);
            store_chunk_l<64, 160, 256>(Sb, wr, tid);
        }
        __syncthreads();
        if (c < 2) {
            load_chunk_g<64, 192, 736, 256>(Ap + (c + 1) * 192, ar, tid);
            load_chunk_g<64, 192, 736, 256>(Wp + (c + 1) * 192, wr, tid);
        } else if (c == 2) {
            load_chunk_g<64, 160, 736, 256>(Ap + 576, ar, tid);
            load_chunk_g<64, 160, 736, 256>(Wp + 576, wr, tid);
        }
        const int nkt = (c == 3) ? 5 : 6;
        for (int kt = 0; kt < nkt; ++kt) {
            bf16x8 a = ld8(Sa + (wave * 16 + llo) * 200 + kt * 32 + quad * 8);
#pragma unroll
            for (int nt = 0; nt < 4; ++nt) {
                bf16x8 b = ld8(Sb + (nt * 16 + llo) * 200 + kt * 32 + quad * 8);
                acc[nt] = MFMA16(a, b, acc[nt]);
            }
        }
    }

#pragma unroll
    for (int nt = 0; nt < 4; ++nt)
#pragma unroll
        for (int r = 0; r < 4; ++r) {
            int m = tm + wave * 16 + quad * 4 + r;
            int n = tn + nt * 16 + llo;
            if (n >= 180) continue;
            float v = acc[nt][r] + bias[n];
            outp[(long)m * 180 + n] = v + resid[(long)m * 180 + n];
        }
}

// ---------------------------------------------------------------------------
extern "C" void kernel_launch(void* const* d_in, const int* in_sizes, int n_in,
                              void* d_out, int out_size, void* d_ws, size_t ws_size,
                              hipStream_t stream) {
    const float* x      = (const float*)d_in[0];
    const float* y      = (const float*)d_in[1];
    const float* n1g    = (const float*)d_in[2];
    const float* n1b    = (const float*)d_in[3];
    const float* kv_w   = (const float*)d_in[4];
    const float* kv_b   = (const float*)d_in[5];
    const float* q_w    = (const float*)d_in[6];
    const float* q_b    = (const float*)d_in[7];
    const float* rpb    = (const float*)d_in[8];
    const float* proj_w = (const float*)d_in[9];
    const float* proj_b = (const float*)d_in[10];
    const float* n2g    = (const float*)d_in[11];
    const float* n2b    = (const float*)d_in[12];
    const float* fc1_w  = (const float*)d_in[13];
    const float* fc1_b  = (const float*)d_in[14];
    const float* fc2_w  = (const float*)d_in[15];
    const float* fc2_b  = (const float*)d_in[16];
    const int*   rpi    = (const int*)d_in[17];

    char* ws = (char*)d_ws;
    bf16* xn    = (bf16*)(ws + 0);          // [32768][192] = xn + yn
    bf16* yn    = (bf16*)(ws + 6291456);
    bf16* qbuf  = (bf16*)(ws + 12582912);   // [16384][192]
    bf16* kvbuf = (bf16*)(ws + 18874368);   // [16384][384]
    bf16* obuf  = (bf16*)(ws + 31457280);   // [16384][192]
    float* xo   = (float*)(ws + 37748736);  // [16384][180] fp32
    bf16* biast = (bf16*)(ws + 49545216);   // [6][16][36][64][4]
    bf16* wkv   = (bf16*)(ws + 51314688);
    bf16* wq    = (bf16*)(ws + 51462144);
    bf16* wproj = (bf16*)(ws + 51560448);
    bf16* wfc1  = (bf16*)(ws + 51658752);
    bf16* wfc2  = (bf16*)(ws + 51953664);
    bf16* hmid  = (bf16*)(ws + 6291456);    // reuse yn/qbuf/kvbuf (dead post-attn)
    bf16* xn2   = xn;                       // xn dead after gemm_kvq

    fused_pre<<<1704, 256, 0, stream>>>(x, y, n1g, n1b, xn,
                                        kv_w, q_w, proj_w, fc1_w, fc2_w, rpb, rpi,
                                        wkv, wq, wproj, wfc1, wfc2, biast);
    gemm_kvq<<<384, 512, 0, stream>>>(xn, yn, wkv, wq, kv_b, q_b, kvbuf, qbuf);
    attn_kernel<<<768, 512, 0, stream>>>(qbuf, kvbuf, biast, obuf);
    gemm_projln<<<256, 256, 0, stream>>>(obuf, wproj, proj_b, x, n2g, n2b, xo, xn2);
    gemm_fc1<<<512, 512, 0, stream>>>(xn2, wfc1, fc1_b, hmid);
    gemm_fc2<<<768, 256, 0, stream>>>(hmid, wfc2, fc2_b, xo, (float*)d_out);
}